// Round 1
// baseline (12948.772 us; speedup 1.0000x reference)
//
#include <hip/hip_runtime.h>

#define C_  512
#define T_  8192
#define M_  5
#define H_  16
#define CM_ (C_ * M_)   // 2560

// ---------------------------------------------------------------------------
// Pre-kernel: hx[t][j] = b1[j] + sum_c x[c,t] * W1[c,j]   (parallel, full GPU)
// x is (C,T) row-major; hx is (T,16).
// ---------------------------------------------------------------------------
__global__ __launch_bounds__(256) void hx_kernel(
    const float* __restrict__ x, const float* __restrict__ W1,
    const float* __restrict__ b1, float* __restrict__ hx)
{
    __shared__ float xs[64][65];                    // [c_local][t_local], padded
    __shared__ __align__(16) float w1s[64][16];
    const int tid = threadIdx.x;
    const int t0  = blockIdx.x * 64;
    const int tl  = tid & 63;                       // local t
    const int jg  = tid >> 6;                       // 0..3 -> j = jg*4 .. jg*4+3

    float acc[4];
#pragma unroll
    for (int jj = 0; jj < 4; ++jj) acc[jj] = b1[jg * 4 + jj];

    for (int c0 = 0; c0 < C_; c0 += 64) {
#pragma unroll
        for (int ii = 0; ii < 16; ++ii) {
            int r = jg * 16 + ii;
            xs[r][tl] = x[(size_t)(c0 + r) * T_ + t0 + tl];   // coalesced
        }
#pragma unroll
        for (int ii = 0; ii < 4; ++ii) {
            int idx = tid * 4 + ii;                 // 0..1023
            ((float*)w1s)[idx] = W1[(size_t)c0 * H_ + idx];   // coalesced
        }
        __syncthreads();
#pragma unroll
        for (int i = 0; i < 64; ++i) {
            float s = xs[i][tl];
            float4 w = *(const float4*)&w1s[i][jg * 4];
            acc[0] = fmaf(s, w.x, acc[0]);
            acc[1] = fmaf(s, w.y, acc[1]);
            acc[2] = fmaf(s, w.z, acc[2]);
            acc[3] = fmaf(s, w.w, acc[3]);
        }
        __syncthreads();
    }
    float4 o; o.x = acc[0]; o.y = acc[1]; o.z = acc[2]; o.w = acc[3];
    *(float4*)&hx[(size_t)(t0 + tl) * H_ + jg * 4] = o;
}

// ---------------------------------------------------------------------------
// Scan kernel: one persistent 512-thread block, thread = channel c.
// Per step (2 barriers):
//   q_c = b2_c + sum_j relu_h[j]*W2[j,c]
//   ema[c,m] = 0.95*ema + 0.05*q_c*K[t,c,m]
//   d_c = sum_m ema*V ; ss_c = sum_m ema^2
//   all-reduce {u_j = sum_c d_c*W1[c,j]} and {nrm = sum ss_c} together
//   scale = 1/(sqrt(nrm) + 1e-12*bias); y_c = scale*d_c
//   relu_h[j] (next step) = max(hx[t+1][j] + scale*u_j, 0)
// ---------------------------------------------------------------------------
#define STEP(TT, PH)                                                          \
  {                                                                           \
    const int tt = (TT);                                                      \
    /* A: q */                                                                \
    float q = b2c;                                                            \
    _Pragma("unroll")                                                         \
    for (int j = 0; j < 16; ++j) q = fmaf(rh[j], w2c[j], q);                  \
    /* B: ema update */                                                       \
    powv *= 0.95f;                                                            \
    const float mq = 0.05f * q;                                               \
    _Pragma("unroll")                                                         \
    for (int m = 0; m < M_; ++m)                                              \
        ema[m] = fmaf(ema[m], 0.95f, mq * kq[PH][m]);                         \
    /* C: d, ss */                                                            \
    float d = 0.f, ss = 0.f;                                                  \
    _Pragma("unroll")                                                         \
    for (int m = 0; m < M_; ++m) {                                            \
        d  = fmaf(ema[m], vq[PH][m], d);                                      \
        ss = fmaf(ema[m], ema[m], ss);                                        \
    }                                                                         \
    /* wave-reduce ss, stash per-wave sums (double-buffered by PH) */         \
    float pss = ss;                                                           \
    _Pragma("unroll")                                                         \
    for (int mk = 1; mk <= 32; mk <<= 1) pss += __shfl_xor(pss, mk, 64);      \
    if (lane == 0) ssb_f[(PH) * 8 + wvid] = pss;                              \
    d_s[c] = d;                                                               \
    /* prefetch K/V for t+2 (off critical path) */                            \
    if (tt + 2 < T_) {                                                        \
        _Pragma("unroll")                                                     \
        for (int m = 0; m < M_; ++m) { kq[PH][m] = kp[m]; vq[PH][m] = vp[m]; }\
        kp += CM_; vp += CM_;                                                 \
    }                                                                         \
    __syncthreads();                                                          \
    /* E: u_j reduction, half-wave j16 owns output j */                       \
    float pu = 0.f;                                                           \
    _Pragma("unroll")                                                         \
    for (int i = 0; i < 16; ++i) pu = fmaf(d_s[k32 + 32 * i], w1r[i], pu);    \
    _Pragma("unroll")                                                         \
    for (int mk = 1; mk <= 16; mk <<= 1) pu += __shfl_xor(pu, mk, 64);        \
    if (k32 == 0) u_f[j16] = pu;                                              \
    __syncthreads();                                                          \
    /* G: finalize scalar, y, next relu_h */                                  \
    float4 s0 = ssb4[(PH) * 2 + 0], s1 = ssb4[(PH) * 2 + 1];                  \
    float nrm = ((s0.x + s0.y) + (s0.z + s0.w)) +                             \
                ((s1.x + s1.y) + (s1.z + s1.w));                              \
    float bias  = 1.0f - powv;                                                \
    float nr    = sqrtf(nrm);                                                 \
    float scale = 1.0f / fmaf(1e-12f, bias, nr);                              \
    float yv = scale * d;                                                     \
    ybuf[(tt & 15) * C_ + c] = yv;                                            \
    float4 uu0 = u44[0], uu1 = u44[1], uu2 = u44[2], uu3 = u44[3];            \
    rh[0]  = fmaxf(fmaf(scale, uu0.x, hq[PH][0].x), 0.f);                     \
    rh[1]  = fmaxf(fmaf(scale, uu0.y, hq[PH][0].y), 0.f);                     \
    rh[2]  = fmaxf(fmaf(scale, uu0.z, hq[PH][0].z), 0.f);                     \
    rh[3]  = fmaxf(fmaf(scale, uu0.w, hq[PH][0].w), 0.f);                     \
    rh[4]  = fmaxf(fmaf(scale, uu1.x, hq[PH][1].x), 0.f);                     \
    rh[5]  = fmaxf(fmaf(scale, uu1.y, hq[PH][1].y), 0.f);                     \
    rh[6]  = fmaxf(fmaf(scale, uu1.z, hq[PH][1].z), 0.f);                     \
    rh[7]  = fmaxf(fmaf(scale, uu1.w, hq[PH][1].w), 0.f);                     \
    rh[8]  = fmaxf(fmaf(scale, uu2.x, hq[PH][2].x), 0.f);                     \
    rh[9]  = fmaxf(fmaf(scale, uu2.y, hq[PH][2].y), 0.f);                     \
    rh[10] = fmaxf(fmaf(scale, uu2.z, hq[PH][2].z), 0.f);                     \
    rh[11] = fmaxf(fmaf(scale, uu2.w, hq[PH][2].w), 0.f);                     \
    rh[12] = fmaxf(fmaf(scale, uu3.x, hq[PH][3].x), 0.f);                     \
    rh[13] = fmaxf(fmaf(scale, uu3.y, hq[PH][3].y), 0.f);                     \
    rh[14] = fmaxf(fmaf(scale, uu3.z, hq[PH][3].z), 0.f);                     \
    rh[15] = fmaxf(fmaf(scale, uu3.w, hq[PH][3].w), 0.f);                     \
    /* refill hx prefetch with hx[t+3] */                                     \
    {                                                                         \
        int tn = tt + 3; if (tn > T_ - 1) tn = T_ - 1;                        \
        const float4* hn = (const float4*)(hx + (size_t)tn * H_);             \
        _Pragma("unroll")                                                     \
        for (int ii = 0; ii < 4; ++ii) hq[PH][ii] = hn[ii];                   \
    }                                                                         \
    /* flush 16 accumulated y's as aligned float4 rows into (C,T) output */   \
    if ((tt & 15) == 15) {                                                    \
        const int tb = tt - 15;                                               \
        _Pragma("unroll")                                                     \
        for (int ii = 0; ii < 4; ++ii) {                                      \
            float4 o;                                                         \
            o.x = ybuf[(4 * ii + 0) * C_ + c];                                \
            o.y = ybuf[(4 * ii + 1) * C_ + c];                                \
            o.z = ybuf[(4 * ii + 2) * C_ + c];                                \
            o.w = ybuf[(4 * ii + 3) * C_ + c];                                \
            *(float4*)(outp + tb + 4 * ii) = o;                               \
        }                                                                     \
    }                                                                         \
  }

__global__ __launch_bounds__(512) void scan_kernel(
    const float* __restrict__ hx, const float* __restrict__ Kp,
    const float* __restrict__ Vp, const float* __restrict__ W1,
    const float* __restrict__ W2, const float* __restrict__ b2,
    float* __restrict__ out)
{
    const int tid  = threadIdx.x;
    const int c    = tid;          // channel
    const int j16  = tid >> 5;     // reduction role: output j (0..15)
    const int k32  = tid & 31;     // lane within half-wave
    const int lane = tid & 63;
    const int wvid = tid >> 6;     // wave id (0..7)

    __shared__ float d_s[C_];
    __shared__ float4 u44[4];                 // u[16]
    __shared__ float4 ssb4[4];                // per-wave ss sums, 2 phases x 8
    __shared__ float ybuf[16 * C_];           // 32 KB y staging
    float* u_f   = (float*)u44;
    float* ssb_f = (float*)ssb4;

    // weights in registers
    float w1r[16], w2c[16];
#pragma unroll
    for (int i = 0; i < 16; ++i) w1r[i] = W1[(size_t)(k32 + 32 * i) * H_ + j16];
#pragma unroll
    for (int j = 0; j < 16; ++j) w2c[j] = W2[(size_t)j * C_ + c];
    const float b2c = b2[c];

    float ema[M_] = {0, 0, 0, 0, 0};
    float powv = 1.0f;

    // K/V prefetch, 2 steps deep
    const float* kp = Kp + c * M_;
    const float* vp = Vp + c * M_;
    float kq[2][M_], vq[2][M_];
#pragma unroll
    for (int m = 0; m < M_; ++m) {
        kq[0][m] = kp[m];        vq[0][m] = vp[m];
        kq[1][m] = kp[CM_ + m];  vq[1][m] = vp[CM_ + m];
    }
    kp += 2 * CM_; vp += 2 * CM_;

    // hx prefetch: hq[0]=hx[1], hq[1]=hx[2]; step t reads hq[t&1]=hx[t+1]
    float4 hq[2][4];
#pragma unroll
    for (int ii = 0; ii < 4; ++ii) {
        hq[0][ii] = ((const float4*)(hx + 1 * H_))[ii];
        hq[1][ii] = ((const float4*)(hx + 2 * H_))[ii];
    }

    // initial relu_h for step 0: y_prev = 0 -> relu(hx[0])
    float rh[16];
#pragma unroll
    for (int ii = 0; ii < 4; ++ii) {
        float4 h0 = ((const float4*)hx)[ii];
        rh[4 * ii + 0] = fmaxf(h0.x, 0.f);
        rh[4 * ii + 1] = fmaxf(h0.y, 0.f);
        rh[4 * ii + 2] = fmaxf(h0.z, 0.f);
        rh[4 * ii + 3] = fmaxf(h0.w, 0.f);
    }

    float* outp = out + (size_t)c * T_;

    for (int t = 0; t < T_; t += 2) {
        STEP(t, 0)
        STEP(t + 1, 1)
    }
}

extern "C" void kernel_launch(void* const* d_in, const int* in_sizes, int n_in,
                              void* d_out, int out_size, void* d_ws, size_t ws_size,
                              hipStream_t stream)
{
    (void)in_sizes; (void)n_in; (void)out_size; (void)ws_size;
    const float* y  = (const float*)d_in[0];   // (1, C, T)
    const float* K  = (const float*)d_in[1];   // (T, C, M)
    const float* V  = (const float*)d_in[2];   // (T, C, M)
    const float* W1 = (const float*)d_in[3];   // (C, H)
    const float* b1 = (const float*)d_in[4];   // (H)
    const float* W2 = (const float*)d_in[5];   // (H, C)
    const float* b2 = (const float*)d_in[6];   // (C)
    float* out = (float*)d_out;                // (1, C, T)
    float* hx  = (float*)d_ws;                 // T*16 floats = 512 KB

    hipLaunchKernelGGL(hx_kernel, dim3(T_ / 64), dim3(256), 0, stream,
                       y, W1, b1, hx);
    hipLaunchKernelGGL(scan_kernel, dim3(1), dim3(512), 0, stream,
                       hx, K, V, W1, W2, b2, out);
}